// Round 3
// baseline (1983.932 us; speedup 1.0000x reference)
//
#include <hip/hip_runtime.h>
#include <stdint.h>

typedef __attribute__((ext_vector_type(8))) short bf16x8;
typedef __attribute__((ext_vector_type(4))) float f32x4;
typedef __attribute__((ext_vector_type(4))) int i32x4;
typedef __attribute__((ext_vector_type(8))) unsigned short u16x8;
typedef __attribute__((ext_vector_type(4))) unsigned short u16x4;

#define DI static __device__ __forceinline__

constexpr int CB = 8;          // batch (total)
constexpr int BCH = 4;         // batches per chunk (2 chunks)
constexpr int CC = 512;        // channels
constexpr int CN = 4096;       // H*W
constexpr int K1 = CC * 9;     // 4608
constexpr int K3 = 3 * K1;     // 13824 (hi*hi, hi*lo, lo*hi thirds)
constexpr int MR = 3 * CC;     // 1536 output rows (q|k|v)
constexpr size_t XSPLIT = (size_t)BCH * 66 * 66 * 512;  // elems per split of padded x (per chunk)

DI unsigned short f2bf(float f) {
  union { float f; uint32_t u; } v; v.f = f;
  uint32_t r = (v.u + 0x7FFFu + ((v.u >> 16) & 1u)) >> 16;  // RNE
  return (unsigned short)r;
}
DI float bf2f(unsigned short h) {
  union { uint32_t u; float f; } v; v.u = ((uint32_t)h) << 16;
  return v.f;
}

// ---- prep 1: padded channels-last hi/lo copies of x (one chunk) ------------
// Xpad[s][b][hh][ww][c], hh,ww in [0,66), data at [1,65); pads are zero (memset
// re-done EVERY chunk: attn/P alias this buffer, so chunk 1 corrupts the pad
// cells that chunk 2 would otherwise inherit -- that was round 2's NaN).
__global__ __launch_bounds__(256) void prep_xpad(const float* __restrict__ x,
                                                 unsigned short* __restrict__ Xpad) {
  int tid = threadIdx.x;
  int w = tid & 63;
  int ccl = tid >> 6;                 // 0..3
  int blk = blockIdx.x;               // 4096 = b(4) * ccg(16) * h(64)
  int h = blk & 63;
  int ccg = (blk >> 6) & 15;
  int b = blk >> 10;                  // 0..3
  int c0 = (ccg * 4 + ccl) * 8;
  const float* xp = x + ((size_t)b * CC) * CN + h * 64 + w;
  u16x8 hi, lo;
#pragma unroll
  for (int j = 0; j < 8; ++j) {
    float v = xp[(size_t)(c0 + j) * CN];
    unsigned short h16 = f2bf(v);
    hi[j] = h16;
    lo[j] = f2bf(v - bf2f(h16));
  }
  size_t po = (((size_t)b * 66 + (h + 1)) * 66 + (w + 1)) * 512 + c0;
  *(u16x8*)&Xpad[po] = hi;
  *(u16x8*)&Xpad[XSPLIT + po] = lo;
}

// ---- prep 2: packed A matrix [1536 x 13824] + bias[1536] -------------------
// k = s*4608 + (ky*3+kx)*512 + c.  q/k rows: s0=W_hi, s1=W_hi, s2=W_lo.
// v rows: s0=bf16(W), s1=s2=0.
__global__ __launch_bounds__(256) void prep_abig(
    const float* __restrict__ wq, const float* __restrict__ wk,
    const float* __restrict__ wv, const float* __restrict__ bq,
    const float* __restrict__ bk, const float* __restrict__ bv,
    unsigned short* __restrict__ Abig, float* __restrict__ bias) {
  unsigned id = blockIdx.x * 256 + threadIdx.x;   // total 1536*13824
  int m = id / K3;
  int kk = id - m * K3;
  int s = kk / K1;
  int r = kk - s * K1;
  int t = r >> 9;
  int c = r & 511;
  int ky = t / 3;
  int kx = t - ky * 3;
  unsigned short oval;
  if (m < 1024) {
    const float* wp = (m < 512) ? wq : wk;
    int mm = (m < 512) ? m : m - 512;
    float wval = wp[(((size_t)mm * 512 + c) * 3 + ky) * 3 + kx];
    unsigned short h16 = f2bf(wval);
    oval = (s < 2) ? h16 : f2bf(wval - bf2f(h16));
  } else {
    oval = 0;
    if (s == 0) oval = f2bf(wv[(((size_t)(m - 1024) * 512 + c) * 3 + ky) * 3 + kx]);
  }
  Abig[id] = oval;
  if (id < 1536) {
    int mm = (int)id;
    bias[mm] = (mm < 512) ? bq[mm] : (mm < 1024) ? bk[mm - 512] : bv[mm - 1024];
  }
}

// ---- unified MFMA GEMM: MODE 0=conv(qkv), 1=QK^T (3-phase split), 2=PV -----
// 128x128 tile, BK=64, 4 waves (2x2), wave tile 64x64 = 4x4 frags of 16x16x32.
// LDS tiles XOR-swizzled (same XOR on write and read sides).
DI int sofs(int row, int kb) { return row * 128 + (kb ^ ((row & 7) << 4)); }

template<int MODE>
__global__ __launch_bounds__(256) void gemm_k(
    const unsigned short* __restrict__ Abig,
    const unsigned short* __restrict__ Xpad,
    const float* __restrict__ bias,
    unsigned short* __restrict__ Qhi, unsigned short* __restrict__ Qlo,
    unsigned short* __restrict__ Khi, unsigned short* __restrict__ Klo,
    unsigned short* __restrict__ Vt,
    float* __restrict__ attn,
    const unsigned short* __restrict__ P,
    const float* __restrict__ xin,
    const float* __restrict__ gamma,
    float* __restrict__ out)
{
  __shared__ __align__(16) unsigned char sA[16384];
  __shared__ __align__(16) unsigned char sB[16384];
  const int tid = threadIdx.x;
  const int lane = tid & 63;
  const int wav = tid >> 6;
  const int wr = wav >> 1, wc = wav & 1;

  int m0, n0, bidx, Kend;
  if constexpr (MODE == 0) {
    int mb = blockIdx.x % 12;         // m fastest: 12 blocks share one B-panel
    int nb = blockIdx.x / 12;         // 0..BCH*32-1
    m0 = mb * 128; n0 = nb * 128;
    bidx = n0 >> 12;                  // 0..BCH-1
    Kend = (m0 >= 1024) ? K1 : K3;    // v rows only need the s=0 third
  } else {
    m0 = (blockIdx.x & 3) * 128;
    n0 = (blockIdx.x >> 2) * 128;
    bidx = blockIdx.z;                // 0..BCH-1
    Kend = (MODE == 1) ? 3 * CN : CC;
  }
  const int nl0 = (MODE == 0) ? (n0 & (CN - 1)) : n0;

  i32x4 ar[4], br[4];

  auto loadAB = [&](int k0) {
#pragma unroll
    for (int q = 0; q < 4; ++q) {
      int ci = q * 256 + tid;
      int row = ci >> 3;              // 0..127
      int ke = (ci & 7) * 8;          // element offset in K
      const unsigned short* ap;
      const unsigned short* bp;
      if constexpr (MODE == 0) {
        ap = Abig + (size_t)(m0 + row) * K3 + (k0 + ke);
        int s = k0 / K1;
        int rr = k0 - s * K1;
        int t = rr >> 9;
        int c0 = rr & 511;
        int ky = t / 3;
        int kx = t - ky * 3;
        int sh = (s == 1) ? 1 : 0;    // thirds pair with X_hi, X_lo, X_hi
        int hh = (nl0 >> 6) + (row >> 6) + ky;   // 0..65
        int wwv = (row & 63) + kx;               // 0..65
        bp = Xpad + (size_t)sh * XSPLIT +
             (((size_t)bidx * 66 + hh) * 66 + wwv) * 512 + (c0 + ke);
      } else if constexpr (MODE == 1) {
        int ph = k0 >> 12;
        int kin = k0 & (CN - 1);
        const unsigned short* Aq = (ph == 2) ? Qlo : Qhi;
        const unsigned short* Bk = (ph == 1) ? Klo : Khi;
        ap = Aq + ((size_t)bidx * CC + (m0 + row)) * CN + (kin + ke);
        bp = Bk + ((size_t)bidx * CC + (n0 + row)) * CN + (kin + ke);
      } else {
        ap = P + ((size_t)bidx * CC + (m0 + row)) * CC + (k0 + ke);
        bp = Vt + ((size_t)bidx * CN + (n0 + row)) * CC + (k0 + ke);
      }
      ar[q] = *(const i32x4*)ap;
      br[q] = *(const i32x4*)bp;
    }
  };

  f32x4 acc[4][4];
  const f32x4 fz = {0.f, 0.f, 0.f, 0.f};
#pragma unroll
  for (int i = 0; i < 4; ++i)
#pragma unroll
    for (int j = 0; j < 4; ++j) acc[i][j] = fz;

  loadAB(0);
  for (int k0 = 0; k0 < Kend; k0 += 64) {
    __syncthreads();                  // previous tile's LDS reads complete
#pragma unroll
    for (int q = 0; q < 4; ++q) {
      int ci = q * 256 + tid;
      int row = ci >> 3;
      int kb = (ci & 7) * 16;         // byte offset in K
      *(i32x4*)&sA[sofs(row, kb)] = ar[q];
      *(i32x4*)&sB[sofs(row, kb)] = br[q];
    }
    __syncthreads();
    if (k0 + 64 < Kend) loadAB(k0 + 64);   // prefetch overlaps MFMA below (T14)
#pragma unroll
    for (int kkp = 0; kkp < 2; ++kkp) {
      bf16x8 af[4], bfv[4];
#pragma unroll
      for (int mf = 0; mf < 4; ++mf)
        af[mf] = *(const bf16x8*)&sA[sofs(wr * 64 + mf * 16 + (lane & 15),
                                          kkp * 64 + (lane >> 4) * 16)];
#pragma unroll
      for (int nf = 0; nf < 4; ++nf)
        bfv[nf] = *(const bf16x8*)&sB[sofs(wc * 64 + nf * 16 + (lane & 15),
                                           kkp * 64 + (lane >> 4) * 16)];
#pragma unroll
      for (int mf = 0; mf < 4; ++mf)
#pragma unroll
        for (int nf = 0; nf < 4; ++nf)
          acc[mf][nf] = __builtin_amdgcn_mfma_f32_16x16x32_bf16(
              af[mf], bfv[nf], acc[mf][nf], 0, 0, 0);
    }
  }

  // ---- epilogue: C/D layout col=lane&15, row=(lane>>4)*4+j ----
  float g = 0.f;
  if constexpr (MODE == 2) g = gamma[0];
#pragma unroll
  for (int mf = 0; mf < 4; ++mf) {
#pragma unroll
    for (int nf = 0; nf < 4; ++nf) {
      f32x4 a = acc[mf][nf];
      int mrow = m0 + wr * 64 + mf * 16 + ((lane >> 4) << 2);
      int ncol = nl0 + wc * 64 + nf * 16 + (lane & 15);
      if constexpr (MODE == 0) {
        if (m0 < 512) {
#pragma unroll
          for (int j = 0; j < 4; ++j) {
            float v = a[j] + bias[mrow + j];
            unsigned short h16 = f2bf(v);
            size_t o = ((size_t)bidx * CC + (mrow + j)) * CN + ncol;
            Qhi[o] = h16;
            Qlo[o] = f2bf(v - bf2f(h16));
          }
        } else if (m0 < 1024) {
#pragma unroll
          for (int j = 0; j < 4; ++j) {
            float v = a[j] + bias[mrow + j];
            unsigned short h16 = f2bf(v);
            size_t o = ((size_t)bidx * CC + (mrow + j - 512)) * CN + ncol;
            Khi[o] = h16;
            Klo[o] = f2bf(v - bf2f(h16));
          }
        } else {
          u16x4 vs;                    // V written transposed: Vt[b][n][d]
#pragma unroll
          for (int j = 0; j < 4; ++j) vs[j] = f2bf(a[j] + bias[mrow + j]);
          *(u16x4*)&Vt[((size_t)bidx * CN + ncol) * CC + (mrow - 1024)] = vs;
        }
      } else if constexpr (MODE == 1) {
#pragma unroll
        for (int j = 0; j < 4; ++j)
          attn[((size_t)bidx * CC + (mrow + j)) * CC + ncol] = a[j];
      } else {
#pragma unroll
        for (int j = 0; j < 4; ++j) {
          size_t o = ((size_t)bidx * CC + (mrow + j)) * CN + ncol;
          out[o] = g * a[j] + xin[o];
        }
      }
    }
  }
}

// ---- softmax over d (512), one wave per row, bf16 output -------------------
__global__ __launch_bounds__(256) void softmax_k(const float* __restrict__ attn,
                                                 unsigned short* __restrict__ P) {
  int row = blockIdx.x * 4 + (threadIdx.x >> 6);   // BCH*512 rows per chunk
  int lane = threadIdx.x & 63;
  const float* rp = attn + (size_t)row * 512 + lane * 8;
  f32x4 a = *(const f32x4*)rp;
  f32x4 b = *(const f32x4*)(rp + 4);
  float mx = fmaxf(fmaxf(fmaxf(a[0], a[1]), fmaxf(a[2], a[3])),
                   fmaxf(fmaxf(b[0], b[1]), fmaxf(b[2], b[3])));
#pragma unroll
  for (int s = 32; s > 0; s >>= 1) mx = fmaxf(mx, __shfl_xor(mx, s, 64));
  float e[8];
  float sum = 0.f;
#pragma unroll
  for (int j = 0; j < 4; ++j) { e[j] = __expf(a[j] - mx); sum += e[j]; }
#pragma unroll
  for (int j = 0; j < 4; ++j) { e[4 + j] = __expf(b[j] - mx); sum += e[4 + j]; }
#pragma unroll
  for (int s = 32; s > 0; s >>= 1) sum += __shfl_xor(sum, s, 64);
  float inv = 1.0f / sum;
  u16x8 o;
#pragma unroll
  for (int j = 0; j < 8; ++j) o[j] = f2bf(e[j] * inv);
  *(u16x8*)&P[(size_t)row * 512 + lane * 8] = o;
}

// ---- diagnostic: fill out with sentinel if workspace is too small ----------
__global__ __launch_bounds__(256) void fill_sentinel(float* __restrict__ out, int n) {
  int i = blockIdx.x * 256 + threadIdx.x;
  if (i < n) out[i] = 1.0e4f;
}

// ---------------------------------------------------------------------------
extern "C" void kernel_launch(void* const* d_in, const int* in_sizes, int n_in,
                              void* d_out, int out_size, void* d_ws, size_t ws_size,
                              hipStream_t stream) {
  (void)in_sizes; (void)n_in;
  const float* x  = (const float*)d_in[0];
  const float* wq = (const float*)d_in[1];
  const float* bq = (const float*)d_in[2];
  const float* wk = (const float*)d_in[3];
  const float* bk = (const float*)d_in[4];
  const float* wv = (const float*)d_in[5];
  const float* bv = (const float*)d_in[6];
  const float* gm = (const float*)d_in[7];
  float* out = (float*)d_out;

  uint8_t* wsp = (uint8_t*)d_ws;
  auto take = [&](size_t bytes) {
    uint8_t* p = wsp;
    wsp += (bytes + 255) & ~(size_t)255;
    return p;
  };
  unsigned short* Xpad = (unsigned short*)take(2 * XSPLIT * sizeof(unsigned short)); // 35.7 MB
  unsigned short* Abig = (unsigned short*)take((size_t)MR * K3 * 2);                 // 42.5 MB
  float* bias          = (float*)take((size_t)MR * 4);
  unsigned short* Khi  = (unsigned short*)take((size_t)BCH * CC * CN * 2);           // 16.8 MB
  unsigned short* Klo  = (unsigned short*)take((size_t)BCH * CC * CN * 2);           // 16.8 MB
  unsigned short* Vt   = (unsigned short*)take((size_t)BCH * CN * CC * 2);           // 16.8 MB
  // attn (f32 [BCH*512*512]) and P (bf16) alias into the Xpad region, which is
  // dead after the conv GEMM of each chunk. Xpad is re-zeroed per chunk below.
  float* attn          = (float*)Xpad;                                   // 4.2 MB
  unsigned short* P    = (unsigned short*)((uint8_t*)Xpad + (size_t)BCH * CC * CC * 4 + 256); // 2.1 MB

  size_t needed = (size_t)(wsp - (uint8_t*)d_ws);   // ~128.5 MB
  if (ws_size < needed) {
    fill_sentinel<<<(out_size + 255) / 256, 256, 0, stream>>>(out, out_size);
    return;
  }

  for (int ch = 0; ch < CB / BCH; ++ch) {
    const float* xch = x + (size_t)ch * BCH * CC * CN;
    float* outch = out + (size_t)ch * BCH * CC * CN;
    // Q (hi|lo bf16 pair) lives in this chunk's d_out region: exactly 33.55 MB.
    unsigned short* Qhi = (unsigned short*)outch;
    unsigned short* Qlo = Qhi + (size_t)BCH * CC * CN;

    // Re-zero Xpad EVERY chunk: chunk 1's attn/P writes corrupted the pad
    // cells (f32 garbage read as bf16 -> Inf/NaN) that chunk 2's conv reads.
    hipMemsetAsync(Xpad, 0, 2 * XSPLIT * sizeof(unsigned short), stream);
    prep_xpad<<<BCH * 16 * 64, 256, 0, stream>>>(xch, Xpad);
    if (ch == 0)
      prep_abig<<<(MR * K3) / 256, 256, 0, stream>>>(wq, wk, wv, bq, bk, bv, Abig, bias);
    gemm_k<0><<<dim3(12 * BCH * 32), 256, 0, stream>>>(Abig, Xpad, bias, Qhi, Qlo,
                                                       Khi, Klo, Vt, attn, P, xch, gm, outch);
    gemm_k<1><<<dim3(16, 1, BCH), 256, 0, stream>>>(Abig, Xpad, bias, Qhi, Qlo,
                                                    Khi, Klo, Vt, attn, P, xch, gm, outch);
    softmax_k<<<BCH * 128, 256, 0, stream>>>(attn, P);
    gemm_k<2><<<dim3(128, 1, BCH), 256, 0, stream>>>(Abig, Xpad, bias, Qhi, Qlo,
                                                     Khi, Klo, Vt, attn, P, xch, gm, outch);
  }
}

// Round 4
// 1833.674 us; speedup vs baseline: 1.0819x; 1.0819x over previous
//
#include <hip/hip_runtime.h>
#include <stdint.h>

typedef __attribute__((ext_vector_type(8))) short bf16x8;
typedef __attribute__((ext_vector_type(4))) float f32x4;
typedef __attribute__((ext_vector_type(4))) int i32x4;
typedef __attribute__((ext_vector_type(8))) unsigned short u16x8;
typedef __attribute__((ext_vector_type(4))) unsigned short u16x4;

#define DI static __device__ __forceinline__

constexpr int CB = 8;          // batch (total)
constexpr int BCH = 4;         // batches per chunk (2 chunks)
constexpr int CC = 512;        // channels
constexpr int CN = 4096;       // H*W
constexpr int K1 = CC * 9;     // 4608
constexpr int K3 = 3 * K1;     // 13824 (hi*hi, hi*lo, lo*hi thirds)
constexpr int MR = 3 * CC;     // 1536 output rows (q|k|v)
constexpr int KSPL = 4;        // QK^T split-K factor
constexpr size_t XSPLIT = (size_t)BCH * 66 * 66 * 512;  // elems per split of padded x (per chunk)

DI unsigned short f2bf(float f) {
  union { float f; uint32_t u; } v; v.f = f;
  uint32_t r = (v.u + 0x7FFFu + ((v.u >> 16) & 1u)) >> 16;  // RNE
  return (unsigned short)r;
}
DI float bf2f(unsigned short h) {
  union { uint32_t u; float f; } v; v.u = ((uint32_t)h) << 16;
  return v.f;
}

// async global->LDS, 16B per lane; LDS dest = wave-uniform base + lane*16
DI void g2lds16(const void* g, void* l) {
  __builtin_amdgcn_global_load_lds((const __attribute__((address_space(1))) void*)g,
                                   (__attribute__((address_space(3))) void*)l, 16, 0, 0);
}

// ---- prep 1: padded channels-last hi/lo copies of x (one chunk) ------------
// Xpad[s][b][hh][ww][c], hh,ww in [0,66), data at [1,65); pads zeroed per chunk
// (attn/P alias this buffer, so chunk 1 corrupts pad cells chunk 2 would read).
__global__ __launch_bounds__(256) void prep_xpad(const float* __restrict__ x,
                                                 unsigned short* __restrict__ Xpad) {
  int tid = threadIdx.x;
  int w = tid & 63;
  int ccl = tid >> 6;                 // 0..3
  int blk = blockIdx.x;               // 4096 = b(4) * ccg(16) * h(64)
  int h = blk & 63;
  int ccg = (blk >> 6) & 15;
  int b = blk >> 10;                  // 0..3
  int c0 = (ccg * 4 + ccl) * 8;
  const float* xp = x + ((size_t)b * CC) * CN + h * 64 + w;
  u16x8 hi, lo;
#pragma unroll
  for (int j = 0; j < 8; ++j) {
    float v = xp[(size_t)(c0 + j) * CN];
    unsigned short h16 = f2bf(v);
    hi[j] = h16;
    lo[j] = f2bf(v - bf2f(h16));
  }
  size_t po = (((size_t)b * 66 + (h + 1)) * 66 + (w + 1)) * 512 + c0;
  *(u16x8*)&Xpad[po] = hi;
  *(u16x8*)&Xpad[XSPLIT + po] = lo;
}

// ---- prep 2: packed A matrix [1536 x 13824] + bias[1536] -------------------
// k = s*4608 + (ky*3+kx)*512 + c.  q/k rows: s0=W_hi, s1=W_hi, s2=W_lo.
// v rows: s0=bf16(W), s1=s2=0.
__global__ __launch_bounds__(256) void prep_abig(
    const float* __restrict__ wq, const float* __restrict__ wk,
    const float* __restrict__ wv, const float* __restrict__ bq,
    const float* __restrict__ bk, const float* __restrict__ bv,
    unsigned short* __restrict__ Abig, float* __restrict__ bias) {
  unsigned id = blockIdx.x * 256 + threadIdx.x;   // total 1536*13824
  int m = id / K3;
  int kk = id - m * K3;
  int s = kk / K1;
  int r = kk - s * K1;
  int t = r >> 9;
  int c = r & 511;
  int ky = t / 3;
  int kx = t - ky * 3;
  unsigned short oval;
  if (m < 1024) {
    const float* wp = (m < 512) ? wq : wk;
    int mm = (m < 512) ? m : m - 512;
    float wval = wp[(((size_t)mm * 512 + c) * 3 + ky) * 3 + kx];
    unsigned short h16 = f2bf(wval);
    oval = (s < 2) ? h16 : f2bf(wval - bf2f(h16));
  } else {
    oval = 0;
    if (s == 0) oval = f2bf(wv[(((size_t)(m - 1024) * 512 + c) * 3 + ky) * 3 + kx]);
  }
  Abig[id] = oval;
  if (id < 1536) {
    int mm = (int)id;
    bias[mm] = (mm < 512) ? bq[mm] : (mm < 1024) ? bk[mm - 512] : bv[mm - 1024];
  }
}

// ---- unified MFMA GEMM: MODE 0=conv(qkv), 1=QK^T (3-phase, split-K), 2=PV --
// 128x128 tile, BK=64, 4 waves (2x2), wave tile 64x64 = 4x4 frags of 16x16x32.
// Staging: global_load_lds w16, linear LDS dest + pre-XORed global source;
// ds_read applies the same XOR -> conflict-free reads (rule #21 both-sides).
DI int sofs(int row, int kb) { return row * 128 + (kb ^ ((row & 7) << 4)); }

template<int MODE>
__global__ __launch_bounds__(256) void gemm_k(
    const unsigned short* __restrict__ Abig,
    const unsigned short* __restrict__ Xpad,
    const float* __restrict__ bias,
    unsigned short* __restrict__ Qhi, unsigned short* __restrict__ Qlo,
    unsigned short* __restrict__ Khi, unsigned short* __restrict__ Klo,
    unsigned short* __restrict__ Vt,
    float* __restrict__ attn,
    const unsigned short* __restrict__ P,
    const float* __restrict__ xin,
    const float* __restrict__ gamma,
    float* __restrict__ out)
{
  __shared__ __align__(16) unsigned char sA[16384];
  __shared__ __align__(16) unsigned char sB[16384];
  const int tid = threadIdx.x;
  const int lane = tid & 63;
  const int wav = tid >> 6;
  const int wr = wav >> 1, wc = wav & 1;

  int m0, n0, bidx, Kbeg = 0, Kend, ks = 0;
  if constexpr (MODE == 0) {
    // bijective XCD swizzle (nwg=384, 384%8==0): each XCD gets 48 consecutive
    // blocks = 12 m-blocks x 4 n-panels -> B reused 12x, A 4x in that XCD's L2.
    constexpr int nwg = 12 * BCH * 32;
    int orig = blockIdx.x;
    int swz = (orig & 7) * (nwg >> 3) + (orig >> 3);
    int mb = swz % 12;                // m fastest: 12 blocks share one B-panel
    int nb = swz / 12;                // 0..BCH*32-1
    m0 = mb * 128; n0 = nb * 128;
    bidx = n0 >> 12;                  // 0..BCH-1
    Kend = (m0 >= 1024) ? K1 : K3;    // v rows only need the s=0 third
  } else if constexpr (MODE == 1) {
    int tile = blockIdx.x & 15;
    ks = blockIdx.x >> 4;             // split-K id, 0..3
    m0 = (tile & 3) * 128;
    n0 = (tile >> 2) * 128;
    bidx = blockIdx.z;                // 0..BCH-1
    Kbeg = ks * (3 * CN / KSPL);
    Kend = Kbeg + (3 * CN / KSPL);
  } else {
    m0 = (blockIdx.x & 3) * 128;
    n0 = (blockIdx.x >> 2) * 128;
    bidx = blockIdx.z;
    Kend = CC;
  }
  const int nl0 = (MODE == 0) ? (n0 & (CN - 1)) : n0;

  auto stage = [&](int k0) {
#pragma unroll
    for (int q = 0; q < 4; ++q) {
      int ci = q * 256 + tid;
      int row = ci >> 3;                       // 0..127
      int ke = ((ci & 7) ^ (row & 7)) * 8;     // pre-swizzled source chunk (elems)
      const unsigned short* ap;
      const unsigned short* bp;
      if constexpr (MODE == 0) {
        ap = Abig + (size_t)(m0 + row) * K3 + (k0 + ke);
        int s = k0 / K1;
        int rr = k0 - s * K1;
        int t = rr >> 9;
        int c0 = rr & 511;
        int ky = t / 3;
        int kx = t - ky * 3;
        int sh = (s == 1) ? 1 : 0;    // thirds pair with X_hi, X_lo, X_hi
        int hh = (nl0 >> 6) + (row >> 6) + ky;   // 0..65
        int wwv = (row & 63) + kx;               // 0..65
        bp = Xpad + (size_t)sh * XSPLIT +
             (((size_t)bidx * 66 + hh) * 66 + wwv) * 512 + (c0 + ke);
      } else if constexpr (MODE == 1) {
        int ph = k0 >> 12;
        int kin = k0 & (CN - 1);
        const unsigned short* Aq = (ph == 2) ? Qlo : Qhi;
        const unsigned short* Bk = (ph == 1) ? Klo : Khi;
        ap = Aq + ((size_t)bidx * CC + (m0 + row)) * CN + (kin + ke);
        bp = Bk + ((size_t)bidx * CC + (n0 + row)) * CN + (kin + ke);
      } else {
        ap = P + ((size_t)bidx * CC + (m0 + row)) * CC + (k0 + ke);
        bp = Vt + ((size_t)bidx * CN + (n0 + row)) * CC + (k0 + ke);
      }
      int wbase = (q * 256 + wav * 64) * 16;   // bytes; wave-uniform LDS base
      g2lds16(ap, sA + wbase);
      g2lds16(bp, sB + wbase);
    }
  };

  f32x4 acc[4][4];
  const f32x4 fz = {0.f, 0.f, 0.f, 0.f};
#pragma unroll
  for (int i = 0; i < 4; ++i)
#pragma unroll
    for (int j = 0; j < 4; ++j) acc[i][j] = fz;

  for (int k0 = Kbeg; k0 < Kend; k0 += 64) {
    stage(k0);                        // async copies into LDS
    __syncthreads();                  // drains vmcnt(0) before barrier
#pragma unroll
    for (int kkp = 0; kkp < 2; ++kkp) {
      bf16x8 af[4], bfv[4];
#pragma unroll
      for (int mf = 0; mf < 4; ++mf)
        af[mf] = *(const bf16x8*)&sA[sofs(wr * 64 + mf * 16 + (lane & 15),
                                          kkp * 64 + (lane >> 4) * 16)];
#pragma unroll
      for (int nf = 0; nf < 4; ++nf)
        bfv[nf] = *(const bf16x8*)&sB[sofs(wc * 64 + nf * 16 + (lane & 15),
                                           kkp * 64 + (lane >> 4) * 16)];
#pragma unroll
      for (int mf = 0; mf < 4; ++mf)
#pragma unroll
        for (int nf = 0; nf < 4; ++nf)
          acc[mf][nf] = __builtin_amdgcn_mfma_f32_16x16x32_bf16(
              af[mf], bfv[nf], acc[mf][nf], 0, 0, 0);
    }
    __syncthreads();                  // LDS reads done before next stage
  }

  // ---- epilogue: C/D layout col=lane&15, row=(lane>>4)*4+j ----
  float g = 0.f;
  if constexpr (MODE == 2) g = gamma[0];
#pragma unroll
  for (int mf = 0; mf < 4; ++mf) {
#pragma unroll
    for (int nf = 0; nf < 4; ++nf) {
      f32x4 a = acc[mf][nf];
      int mrow = m0 + wr * 64 + mf * 16 + ((lane >> 4) << 2);
      int ncol = nl0 + wc * 64 + nf * 16 + (lane & 15);
      if constexpr (MODE == 0) {
        if (m0 < 512) {
#pragma unroll
          for (int j = 0; j < 4; ++j) {
            float v = a[j] + bias[mrow + j];
            unsigned short h16 = f2bf(v);
            size_t o = ((size_t)bidx * CC + (mrow + j)) * CN + ncol;
            Qhi[o] = h16;
            Qlo[o] = f2bf(v - bf2f(h16));
          }
        } else if (m0 < 1024) {
#pragma unroll
          for (int j = 0; j < 4; ++j) {
            float v = a[j] + bias[mrow + j];
            unsigned short h16 = f2bf(v);
            size_t o = ((size_t)bidx * CC + (mrow + j - 512)) * CN + ncol;
            Khi[o] = h16;
            Klo[o] = f2bf(v - bf2f(h16));
          }
        } else {
          u16x4 vs;                    // V written transposed: Vt[b][n][d]
#pragma unroll
          for (int j = 0; j < 4; ++j) vs[j] = f2bf(a[j] + bias[mrow + j]);
          *(u16x4*)&Vt[((size_t)bidx * CN + ncol) * CC + (mrow - 1024)] = vs;
        }
      } else if constexpr (MODE == 1) {
        size_t pbase = (size_t)ks * ((size_t)BCH * CC * CC);
#pragma unroll
        for (int j = 0; j < 4; ++j)
          attn[pbase + ((size_t)bidx * CC + (mrow + j)) * CC + ncol] = a[j];
      } else {
#pragma unroll
        for (int j = 0; j < 4; ++j) {
          size_t o = ((size_t)bidx * CC + (mrow + j)) * CN + ncol;
          out[o] = g * a[j] + xin[o];
        }
      }
    }
  }
}

// ---- softmax over d (512): sum KSPL split-K partials, one wave per row -----
__global__ __launch_bounds__(256) void softmax_k(const float* __restrict__ attn,
                                                 unsigned short* __restrict__ P) {
  int row = blockIdx.x * 4 + (threadIdx.x >> 6);   // BCH*512 rows per chunk
  int lane = threadIdx.x & 63;
  constexpr size_t PS = (size_t)BCH * CC * CC;
  const float* rp = attn + (size_t)row * 512 + lane * 8;
  f32x4 a = {0.f, 0.f, 0.f, 0.f};
  f32x4 b = {0.f, 0.f, 0.f, 0.f};
#pragma unroll
  for (int ksp = 0; ksp < KSPL; ++ksp) {
    a += *(const f32x4*)(rp + (size_t)ksp * PS);
    b += *(const f32x4*)(rp + (size_t)ksp * PS + 4);
  }
  float mx = fmaxf(fmaxf(fmaxf(a[0], a[1]), fmaxf(a[2], a[3])),
                   fmaxf(fmaxf(b[0], b[1]), fmaxf(b[2], b[3])));
#pragma unroll
  for (int s = 32; s > 0; s >>= 1) mx = fmaxf(mx, __shfl_xor(mx, s, 64));
  float e[8];
  float sum = 0.f;
#pragma unroll
  for (int j = 0; j < 4; ++j) { e[j] = __expf(a[j] - mx); sum += e[j]; }
#pragma unroll
  for (int j = 0; j < 4; ++j) { e[4 + j] = __expf(b[j] - mx); sum += e[4 + j]; }
#pragma unroll
  for (int s = 32; s > 0; s >>= 1) sum += __shfl_xor(sum, s, 64);
  float inv = 1.0f / sum;
  u16x8 o;
#pragma unroll
  for (int j = 0; j < 8; ++j) o[j] = f2bf(e[j] * inv);
  *(u16x8*)&P[(size_t)row * 512 + lane * 8] = o;
}

// ---- diagnostic: fill out with sentinel if workspace is too small ----------
__global__ __launch_bounds__(256) void fill_sentinel(float* __restrict__ out, int n) {
  int i = blockIdx.x * 256 + threadIdx.x;
  if (i < n) out[i] = 1.0e4f;
}

// ---------------------------------------------------------------------------
extern "C" void kernel_launch(void* const* d_in, const int* in_sizes, int n_in,
                              void* d_out, int out_size, void* d_ws, size_t ws_size,
                              hipStream_t stream) {
  (void)in_sizes; (void)n_in;
  const float* x  = (const float*)d_in[0];
  const float* wq = (const float*)d_in[1];
  const float* bq = (const float*)d_in[2];
  const float* wk = (const float*)d_in[3];
  const float* bk = (const float*)d_in[4];
  const float* wv = (const float*)d_in[5];
  const float* bv = (const float*)d_in[6];
  const float* gm = (const float*)d_in[7];
  float* out = (float*)d_out;

  uint8_t* wsp = (uint8_t*)d_ws;
  auto take = [&](size_t bytes) {
    uint8_t* p = wsp;
    wsp += (bytes + 255) & ~(size_t)255;
    return p;
  };
  unsigned short* Xpad = (unsigned short*)take(2 * XSPLIT * sizeof(unsigned short)); // 35.7 MB
  unsigned short* Abig = (unsigned short*)take((size_t)MR * K3 * 2);                 // 42.5 MB
  float* bias          = (float*)take((size_t)MR * 4);
  unsigned short* Khi  = (unsigned short*)take((size_t)BCH * CC * CN * 2);           // 16.8 MB
  unsigned short* Klo  = (unsigned short*)take((size_t)BCH * CC * CN * 2);           // 16.8 MB
  unsigned short* Vt   = (unsigned short*)take((size_t)BCH * CN * CC * 2);           // 16.8 MB
  // attn (KSPL f32 partials, 16.8 MB) and P (bf16, 2.1 MB) alias the Xpad
  // region, which is dead after each chunk's conv GEMM. Xpad re-zeroed/chunk.
  float* attn          = (float*)Xpad;
  unsigned short* P    = (unsigned short*)((uint8_t*)Xpad +
                           (size_t)KSPL * BCH * CC * CC * 4 + 256);

  size_t needed = (size_t)(wsp - (uint8_t*)d_ws);   // ~128.5 MB
  if (ws_size < needed) {
    fill_sentinel<<<(out_size + 255) / 256, 256, 0, stream>>>(out, out_size);
    return;
  }

  for (int ch = 0; ch < CB / BCH; ++ch) {
    const float* xch = x + (size_t)ch * BCH * CC * CN;
    float* outch = out + (size_t)ch * BCH * CC * CN;
    // Q (hi|lo bf16 pair) lives in this chunk's d_out region: exactly 33.55 MB.
    unsigned short* Qhi = (unsigned short*)outch;
    unsigned short* Qlo = Qhi + (size_t)BCH * CC * CN;

    // Re-zero Xpad EVERY chunk: chunk 1's attn/P writes corrupted the pad
    // cells (f32 garbage read as bf16 -> Inf/NaN) that chunk 2's conv reads.
    hipMemsetAsync(Xpad, 0, 2 * XSPLIT * sizeof(unsigned short), stream);
    prep_xpad<<<BCH * 16 * 64, 256, 0, stream>>>(xch, Xpad);
    if (ch == 0)
      prep_abig<<<(MR * K3) / 256, 256, 0, stream>>>(wq, wk, wv, bq, bk, bv, Abig, bias);
    gemm_k<0><<<dim3(12 * BCH * 32), 256, 0, stream>>>(Abig, Xpad, bias, Qhi, Qlo,
                                                       Khi, Klo, Vt, attn, P, xch, gm, outch);
    gemm_k<1><<<dim3(16 * KSPL, 1, BCH), 256, 0, stream>>>(Abig, Xpad, bias, Qhi, Qlo,
                                                           Khi, Klo, Vt, attn, P, xch, gm, outch);
    softmax_k<<<BCH * 128, 256, 0, stream>>>(attn, P);
    gemm_k<2><<<dim3(128, 1, BCH), 256, 0, stream>>>(Abig, Xpad, bias, Qhi, Qlo,
                                                     Khi, Klo, Vt, attn, P, xch, gm, outch);
  }
}

// Round 5
// 1576.152 us; speedup vs baseline: 1.2587x; 1.1634x over previous
//
#include <hip/hip_runtime.h>
#include <stdint.h>

typedef __attribute__((ext_vector_type(8))) short bf16x8;
typedef __attribute__((ext_vector_type(4))) float f32x4;
typedef __attribute__((ext_vector_type(4))) int i32x4;
typedef __attribute__((ext_vector_type(8))) unsigned short u16x8;
typedef __attribute__((ext_vector_type(4))) unsigned short u16x4;

#define DI static __device__ __forceinline__

constexpr int CB = 8;          // batch (total)
constexpr int BCH = 4;         // batches per chunk (2 chunks)
constexpr int CC = 512;        // channels
constexpr int CN = 4096;       // H*W
constexpr int K1 = CC * 9;     // 4608
constexpr int K2 = 2 * K1;     // 9216: packed A = [W_hi | W_lo] (s0,s1 share W_hi)
constexpr int MR = 3 * CC;     // 1536 output rows (q|k|v)
constexpr int KSPL = 4;        // QK^T split-K factor
constexpr size_t XSPLIT = (size_t)BCH * 66 * 66 * 512;  // elems per split of padded x (per chunk)

DI unsigned short f2bf(float f) {
  union { float f; uint32_t u; } v; v.f = f;
  uint32_t r = (v.u + 0x7FFFu + ((v.u >> 16) & 1u)) >> 16;  // RNE
  return (unsigned short)r;
}
DI float bf2f(unsigned short h) {
  union { uint32_t u; float f; } v; v.u = ((uint32_t)h) << 16;
  return v.f;
}

// async global->LDS, 16B per lane; LDS dest = wave-uniform base + lane*16
DI void g2lds16(const void* g, void* l) {
  __builtin_amdgcn_global_load_lds((const __attribute__((address_space(1))) void*)g,
                                   (__attribute__((address_space(3))) void*)l, 16, 0, 0);
}

// ---- prep 1: padded channels-last hi/lo copies of x (one chunk) ------------
__global__ __launch_bounds__(256) void prep_xpad(const float* __restrict__ x,
                                                 unsigned short* __restrict__ Xpad) {
  int tid = threadIdx.x;
  int w = tid & 63;
  int ccl = tid >> 6;                 // 0..3
  int blk = blockIdx.x;               // 4096 = b(4) * ccg(16) * h(64)
  int h = blk & 63;
  int ccg = (blk >> 6) & 15;
  int b = blk >> 10;                  // 0..3
  int c0 = (ccg * 4 + ccl) * 8;
  const float* xp = x + ((size_t)b * CC) * CN + h * 64 + w;
  u16x8 hi, lo;
#pragma unroll
  for (int j = 0; j < 8; ++j) {
    float v = xp[(size_t)(c0 + j) * CN];
    unsigned short h16 = f2bf(v);
    hi[j] = h16;
    lo[j] = f2bf(v - bf2f(h16));
  }
  size_t po = (((size_t)b * 66 + (h + 1)) * 66 + (w + 1)) * 512 + c0;
  *(u16x8*)&Xpad[po] = hi;
  *(u16x8*)&Xpad[XSPLIT + po] = lo;
}

// ---- prep 2: packed A matrix [1536 x 9216] + bias[1536] --------------------
// third 0 = W_hi (q/k) or bf16(W) (v); third 1 = W_lo (q/k) or 0 (v, unread).
__global__ __launch_bounds__(256) void prep_abig(
    const float* __restrict__ wq, const float* __restrict__ wk,
    const float* __restrict__ wv, const float* __restrict__ bq,
    const float* __restrict__ bk, const float* __restrict__ bv,
    unsigned short* __restrict__ Abig, float* __restrict__ bias) {
  unsigned id = blockIdx.x * 256 + threadIdx.x;   // total 1536*9216
  int m = id / K2;
  int kk = id - m * K2;
  int third = kk / K1;
  int r = kk - third * K1;
  int t = r >> 9;
  int c = r & 511;
  int ky = t / 3;
  int kx = t - ky * 3;
  unsigned short oval;
  if (m < 1024) {
    const float* wp = (m < 512) ? wq : wk;
    int mm = (m < 512) ? m : m - 512;
    float wval = wp[(((size_t)mm * 512 + c) * 3 + ky) * 3 + kx];
    unsigned short h16 = f2bf(wval);
    oval = (third == 0) ? h16 : f2bf(wval - bf2f(h16));
  } else {
    oval = 0;
    if (third == 0) oval = f2bf(wv[(((size_t)(m - 1024) * 512 + c) * 3 + ky) * 3 + kx]);
  }
  Abig[id] = oval;
  if (id < 1536) {
    int mm = (int)id;
    bias[mm] = (mm < 512) ? bq[mm] : (mm < 1024) ? bk[mm - 512] : bv[mm - 1024];
  }
}

// XOR swizzle shared by all LDS tiles (write side pre-swizzles the SOURCE,
// dest stays linear; read side applies the same XOR -> conflict-free).
DI int sofs(int row, int kb) { return row * 128 + (kb ^ ((row & 7) << 4)); }

// ---- conv GEMM (qkv), division-free addressing -----------------------------
// 128x128 tile, BK=64, 4 waves (2x2), wave tile 64x64 = 4x4 frags of 16x16x32.
// K order: s (split product) / t=3*ky+kx (tap) / c0 (channel block of 64).
// s0: W_hi*X_hi, s1: W_hi*X_lo, s2: W_lo*X_hi. v rows: s0 only.
__global__ __launch_bounds__(256, 4) void conv_k(
    const unsigned short* __restrict__ Abig,
    const unsigned short* __restrict__ Xpad,
    const float* __restrict__ bias,
    unsigned short* __restrict__ Qhi, unsigned short* __restrict__ Qlo,
    unsigned short* __restrict__ Khi, unsigned short* __restrict__ Klo,
    unsigned short* __restrict__ Vt)
{
  __shared__ __align__(16) unsigned char sA[16384];
  __shared__ __align__(16) unsigned char sB[16384];
  const int tid = threadIdx.x;
  const int lane = tid & 63;
  const int wav = tid >> 6;
  const int wr = wav >> 1, wc = wav & 1;

  // bijective XCD swizzle (nwg=1536, %8==0): 192 consecutive swz per XCD =
  // 16 n-panels x 12 m-blocks -> B panel L2-reused 12x, A reused 16x per XCD.
  constexpr int nwg = 12 * BCH * 32;
  int orig = blockIdx.x;
  int swz = (orig & 7) * (nwg >> 3) + (orig >> 3);
  int mb = swz % 12;
  int nb = swz / 12;
  const int m0 = mb * 128, n0 = nb * 128;
  const int bidx = n0 >> 12;          // 0..BCH-1
  const int nl0 = n0 & (CN - 1);
  const int sEnd = (m0 >= 1024) ? 1 : 3;

  // per-thread staging bases (computed ONCE)
  const unsigned short* aBase[4];
  const unsigned short* bBase[4];
  int wbaseq[4];
#pragma unroll
  for (int q = 0; q < 4; ++q) {
    int ci = q * 256 + tid;
    int row = ci >> 3;                        // 0..127
    int ke = ((ci & 7) ^ (row & 7)) * 8;      // pre-swizzled source chunk
    aBase[q] = Abig + (size_t)(m0 + row) * K2 + ke;
    bBase[q] = Xpad + (((size_t)bidx * 66 + (nl0 >> 6)) * 66) * 512
             + ((row >> 6) * 66 + (row & 63)) * 512 + ke;
    wbaseq[q] = (q * 256 + wav * 64) * 16;    // wave-uniform LDS byte base
  }

  f32x4 acc[4][4];
  const f32x4 fz = {0.f, 0.f, 0.f, 0.f};
#pragma unroll
  for (int i = 0; i < 4; ++i)
#pragma unroll
    for (int j = 0; j < 4; ++j) acc[i][j] = fz;

  for (int s = 0; s < sEnd; ++s) {
    const int aT = (s == 2) ? K1 : 0;         // A third: s0,s1 -> W_hi, s2 -> W_lo
    const size_t shOfs = (s == 1) ? XSPLIT : 0;  // X split: s1 -> X_lo
    int ky = 0, kx = 0;
    for (int t = 0; t < 9; ++t) {
      const int aStepT = aT + t * 512;
      const size_t bStepT = shOfs + (size_t)(ky * 66 + kx) * 512;
      for (int c0 = 0; c0 < 512; c0 += 64) {
#pragma unroll
        for (int q = 0; q < 4; ++q) {
          g2lds16(aBase[q] + aStepT + c0, sA + wbaseq[q]);
          g2lds16(bBase[q] + bStepT + c0, sB + wbaseq[q]);
        }
        __syncthreads();                      // drains vmcnt(0) before barrier
#pragma unroll
        for (int kkp = 0; kkp < 2; ++kkp) {
          bf16x8 af[4], bfv[4];
#pragma unroll
          for (int mf = 0; mf < 4; ++mf)
            af[mf] = *(const bf16x8*)&sA[sofs(wr * 64 + mf * 16 + (lane & 15),
                                              kkp * 64 + (lane >> 4) * 16)];
#pragma unroll
          for (int nf = 0; nf < 4; ++nf)
            bfv[nf] = *(const bf16x8*)&sB[sofs(wc * 64 + nf * 16 + (lane & 15),
                                               kkp * 64 + (lane >> 4) * 16)];
#pragma unroll
          for (int mf = 0; mf < 4; ++mf)
#pragma unroll
            for (int nf = 0; nf < 4; ++nf)
              acc[mf][nf] = __builtin_amdgcn_mfma_f32_16x16x32_bf16(
                  af[mf], bfv[nf], acc[mf][nf], 0, 0, 0);
        }
        __syncthreads();                      // LDS reads done before next stage
      }
      if (++kx == 3) { kx = 0; ++ky; }
    }
  }

  // ---- epilogue: C/D layout col=lane&15, row=(lane>>4)*4+j ----
#pragma unroll
  for (int mf = 0; mf < 4; ++mf) {
#pragma unroll
    for (int nf = 0; nf < 4; ++nf) {
      f32x4 a = acc[mf][nf];
      int mrow = m0 + wr * 64 + mf * 16 + ((lane >> 4) << 2);
      int ncol = nl0 + wc * 64 + nf * 16 + (lane & 15);
      if (m0 < 512) {
#pragma unroll
        for (int j = 0; j < 4; ++j) {
          float v = a[j] + bias[mrow + j];
          unsigned short h16 = f2bf(v);
          size_t o = ((size_t)bidx * CC + (mrow + j)) * CN + ncol;
          Qhi[o] = h16;
          Qlo[o] = f2bf(v - bf2f(h16));
        }
      } else if (m0 < 1024) {
#pragma unroll
        for (int j = 0; j < 4; ++j) {
          float v = a[j] + bias[mrow + j];
          unsigned short h16 = f2bf(v);
          size_t o = ((size_t)bidx * CC + (mrow + j - 512)) * CN + ncol;
          Khi[o] = h16;
          Klo[o] = f2bf(v - bf2f(h16));
        }
      } else {
        u16x4 vs;                    // V written transposed: Vt[b][n][d]
#pragma unroll
        for (int j = 0; j < 4; ++j) vs[j] = f2bf(a[j] + bias[mrow + j]);
        *(u16x4*)&Vt[((size_t)bidx * CN + ncol) * CC + (mrow - 1024)] = vs;
      }
    }
  }
}

// ---- MFMA GEMM: MODE 1=QK^T (3-phase hi/lo, split-K), 2=PV -----------------
template<int MODE>
__global__ __launch_bounds__(256) void gemm_k(
    const unsigned short* __restrict__ Qhi, const unsigned short* __restrict__ Qlo,
    const unsigned short* __restrict__ Khi, const unsigned short* __restrict__ Klo,
    const unsigned short* __restrict__ Vt,
    float* __restrict__ attn,
    const unsigned short* __restrict__ P,
    const float* __restrict__ xin,
    const float* __restrict__ gamma,
    float* __restrict__ out)
{
  __shared__ __align__(16) unsigned char sA[16384];
  __shared__ __align__(16) unsigned char sB[16384];
  const int tid = threadIdx.x;
  const int lane = tid & 63;
  const int wav = tid >> 6;
  const int wr = wav >> 1, wc = wav & 1;

  int m0, n0, bidx, Kbeg = 0, Kend, ks = 0;
  if constexpr (MODE == 1) {
    int tile = blockIdx.x & 15;
    ks = blockIdx.x >> 4;             // split-K id, 0..3
    m0 = (tile & 3) * 128;
    n0 = (tile >> 2) * 128;
    bidx = blockIdx.z;                // 0..BCH-1
    Kbeg = ks * (3 * CN / KSPL);
    Kend = Kbeg + (3 * CN / KSPL);
  } else {
    m0 = (blockIdx.x & 3) * 128;
    n0 = (blockIdx.x >> 2) * 128;
    bidx = blockIdx.z;
    Kend = CC;
  }

  auto stage = [&](int k0) {
#pragma unroll
    for (int q = 0; q < 4; ++q) {
      int ci = q * 256 + tid;
      int row = ci >> 3;                       // 0..127
      int ke = ((ci & 7) ^ (row & 7)) * 8;     // pre-swizzled source chunk
      const unsigned short* ap;
      const unsigned short* bp;
      if constexpr (MODE == 1) {
        int ph = k0 >> 12;
        int kin = k0 & (CN - 1);
        const unsigned short* Aq = (ph == 2) ? Qlo : Qhi;
        const unsigned short* Bk = (ph == 1) ? Klo : Khi;
        ap = Aq + ((size_t)bidx * CC + (m0 + row)) * CN + (kin + ke);
        bp = Bk + ((size_t)bidx * CC + (n0 + row)) * CN + (kin + ke);
      } else {
        ap = P + ((size_t)bidx * CC + (m0 + row)) * CC + (k0 + ke);
        bp = Vt + ((size_t)bidx * CN + (n0 + row)) * CC + (k0 + ke);
      }
      int wbase = (q * 256 + wav * 64) * 16;   // wave-uniform LDS base
      g2lds16(ap, sA + wbase);
      g2lds16(bp, sB + wbase);
    }
  };

  f32x4 acc[4][4];
  const f32x4 fz = {0.f, 0.f, 0.f, 0.f};
#pragma unroll
  for (int i = 0; i < 4; ++i)
#pragma unroll
    for (int j = 0; j < 4; ++j) acc[i][j] = fz;

  for (int k0 = Kbeg; k0 < Kend; k0 += 64) {
    stage(k0);
    __syncthreads();
#pragma unroll
    for (int kkp = 0; kkp < 2; ++kkp) {
      bf16x8 af[4], bfv[4];
#pragma unroll
      for (int mf = 0; mf < 4; ++mf)
        af[mf] = *(const bf16x8*)&sA[sofs(wr * 64 + mf * 16 + (lane & 15),
                                          kkp * 64 + (lane >> 4) * 16)];
#pragma unroll
      for (int nf = 0; nf < 4; ++nf)
        bfv[nf] = *(const bf16x8*)&sB[sofs(wc * 64 + nf * 16 + (lane & 15),
                                           kkp * 64 + (lane >> 4) * 16)];
#pragma unroll
      for (int mf = 0; mf < 4; ++mf)
#pragma unroll
        for (int nf = 0; nf < 4; ++nf)
          acc[mf][nf] = __builtin_amdgcn_mfma_f32_16x16x32_bf16(
              af[mf], bfv[nf], acc[mf][nf], 0, 0, 0);
    }
    __syncthreads();
  }

  float g = 0.f;
  if constexpr (MODE == 2) g = gamma[0];
#pragma unroll
  for (int mf = 0; mf < 4; ++mf) {
#pragma unroll
    for (int nf = 0; nf < 4; ++nf) {
      f32x4 a = acc[mf][nf];
      int mrow = m0 + wr * 64 + mf * 16 + ((lane >> 4) << 2);
      int ncol = n0 + wc * 64 + nf * 16 + (lane & 15);
      if constexpr (MODE == 1) {
        size_t pbase = (size_t)ks * ((size_t)BCH * CC * CC);
#pragma unroll
        for (int j = 0; j < 4; ++j)
          attn[pbase + ((size_t)bidx * CC + (mrow + j)) * CC + ncol] = a[j];
      } else {
#pragma unroll
        for (int j = 0; j < 4; ++j) {
          size_t o = ((size_t)bidx * CC + (mrow + j)) * CN + ncol;
          out[o] = g * a[j] + xin[o];
        }
      }
    }
  }
}

// ---- softmax over d (512): sum KSPL split-K partials, one wave per row -----
__global__ __launch_bounds__(256) void softmax_k(const float* __restrict__ attn,
                                                 unsigned short* __restrict__ P) {
  int row = blockIdx.x * 4 + (threadIdx.x >> 6);   // BCH*512 rows per chunk
  int lane = threadIdx.x & 63;
  constexpr size_t PS = (size_t)BCH * CC * CC;
  const float* rp = attn + (size_t)row * 512 + lane * 8;
  f32x4 a = {0.f, 0.f, 0.f, 0.f};
  f32x4 b = {0.f, 0.f, 0.f, 0.f};
#pragma unroll
  for (int ksp = 0; ksp < KSPL; ++ksp) {
    a += *(const f32x4*)(rp + (size_t)ksp * PS);
    b += *(const f32x4*)(rp + (size_t)ksp * PS + 4);
  }
  float mx = fmaxf(fmaxf(fmaxf(a[0], a[1]), fmaxf(a[2], a[3])),
                   fmaxf(fmaxf(b[0], b[1]), fmaxf(b[2], b[3])));
#pragma unroll
  for (int s = 32; s > 0; s >>= 1) mx = fmaxf(mx, __shfl_xor(mx, s, 64));
  float e[8];
  float sum = 0.f;
#pragma unroll
  for (int j = 0; j < 4; ++j) { e[j] = __expf(a[j] - mx); sum += e[j]; }
#pragma unroll
  for (int j = 0; j < 4; ++j) { e[4 + j] = __expf(b[j] - mx); sum += e[4 + j]; }
#pragma unroll
  for (int s = 32; s > 0; s >>= 1) sum += __shfl_xor(sum, s, 64);
  float inv = 1.0f / sum;
  u16x8 o;
#pragma unroll
  for (int j = 0; j < 8; ++j) o[j] = f2bf(e[j] * inv);
  *(u16x8*)&P[(size_t)row * 512 + lane * 8] = o;
}

// ---- diagnostic: fill out with sentinel if workspace is too small ----------
__global__ __launch_bounds__(256) void fill_sentinel(float* __restrict__ out, int n) {
  int i = blockIdx.x * 256 + threadIdx.x;
  if (i < n) out[i] = 1.0e4f;
}

// ---------------------------------------------------------------------------
extern "C" void kernel_launch(void* const* d_in, const int* in_sizes, int n_in,
                              void* d_out, int out_size, void* d_ws, size_t ws_size,
                              hipStream_t stream) {
  (void)in_sizes; (void)n_in;
  const float* x  = (const float*)d_in[0];
  const float* wq = (const float*)d_in[1];
  const float* bq = (const float*)d_in[2];
  const float* wk = (const float*)d_in[3];
  const float* bk = (const float*)d_in[4];
  const float* wv = (const float*)d_in[5];
  const float* bv = (const float*)d_in[6];
  const float* gm = (const float*)d_in[7];
  float* out = (float*)d_out;

  uint8_t* wsp = (uint8_t*)d_ws;
  auto take = [&](size_t bytes) {
    uint8_t* p = wsp;
    wsp += (bytes + 255) & ~(size_t)255;
    return p;
  };
  unsigned short* Xpad = (unsigned short*)take(2 * XSPLIT * sizeof(unsigned short)); // 35.7 MB
  unsigned short* Abig = (unsigned short*)take((size_t)MR * K2 * 2);                 // 28.3 MB
  float* bias          = (float*)take((size_t)MR * 4);
  unsigned short* Khi  = (unsigned short*)take((size_t)BCH * CC * CN * 2);           // 16.8 MB
  unsigned short* Klo  = (unsigned short*)take((size_t)BCH * CC * CN * 2);           // 16.8 MB
  unsigned short* Vt   = (unsigned short*)take((size_t)BCH * CN * CC * 2);           // 16.8 MB
  // attn (KSPL f32 partials) + P (bf16) alias the Xpad region (dead after each
  // chunk's conv). Xpad re-zeroed per chunk to heal the corrupted pad cells.
  float* attn          = (float*)Xpad;
  unsigned short* P    = (unsigned short*)((uint8_t*)Xpad +
                           (size_t)KSPL * BCH * CC * CC * 4 + 256);

  size_t needed = (size_t)(wsp - (uint8_t*)d_ws);   // ~114.5 MB
  if (ws_size < needed) {
    fill_sentinel<<<(out_size + 255) / 256, 256, 0, stream>>>(out, out_size);
    return;
  }

  for (int ch = 0; ch < CB / BCH; ++ch) {
    const float* xch = x + (size_t)ch * BCH * CC * CN;
    float* outch = out + (size_t)ch * BCH * CC * CN;
    // Q (hi|lo bf16 pair) lives in this chunk's d_out region: exactly 33.55 MB.
    unsigned short* Qhi = (unsigned short*)outch;
    unsigned short* Qlo = Qhi + (size_t)BCH * CC * CN;

    hipMemsetAsync(Xpad, 0, 2 * XSPLIT * sizeof(unsigned short), stream);
    prep_xpad<<<BCH * 16 * 64, 256, 0, stream>>>(xch, Xpad);
    if (ch == 0)
      prep_abig<<<(MR * K2) / 256, 256, 0, stream>>>(wq, wk, wv, bq, bk, bv, Abig, bias);
    conv_k<<<dim3(12 * BCH * 32), 256, 0, stream>>>(Abig, Xpad, bias, Qhi, Qlo,
                                                    Khi, Klo, Vt);
    gemm_k<1><<<dim3(16 * KSPL, 1, BCH), 256, 0, stream>>>(Qhi, Qlo, Khi, Klo, Vt,
                                                           attn, P, xch, gm, outch);
    softmax_k<<<BCH * 128, 256, 0, stream>>>(attn, P);
    gemm_k<2><<<dim3(128, 1, BCH), 256, 0, stream>>>(Qhi, Qlo, Khi, Klo, Vt,
                                                     attn, P, xch, gm, outch);
  }
}